// Round 7
// baseline (1543.210 us; speedup 1.0000x reference)
//
#include <hip/hip_runtime.h>
#include <cstdint>
#include <cstddef>

#define DEV __device__ __forceinline__

typedef __attribute__((ext_vector_type(4))) float    f32x4;
typedef __attribute__((ext_vector_type(4))) _Float16 f16x4;
typedef __attribute__((ext_vector_type(8))) _Float16 f16x8;

static constexpr int B_ = 128, T_ = 1024, F_ = 128, H_ = 128, L_ = 7;
static constexpr int M_ = B_ * T_;       // 131072

// ---------- numeric helpers ----------
DEV float fexp2(float x){
#if __has_builtin(__builtin_amdgcn_exp2f)
  return __builtin_amdgcn_exp2f(x);
#else
  return exp2f(x);
#endif
}
DEV float frcp(float x){
#if __has_builtin(__builtin_amdgcn_rcpf)
  return __builtin_amdgcn_rcpf(x);
#else
  return 1.0f/x;
#endif
}
DEV float fsig(float x){ return frcp(1.f + fexp2(-1.44269504f*x)); }
DEV float ftanh(float x){
  x = fminf(10.f, fmaxf(-10.f, x));
  float e = fexp2(2.88539008f*x);
  return (e - 1.f) * frcp(e + 1.f);
}
DEV f16x4 ntld4(const _Float16* p){ return __builtin_nontemporal_load((const f16x4*)p); }
DEV void  ntst4(_Float16* p, f16x4 v){ __builtin_nontemporal_store(v, (f16x4*)p); }
DEV f16x8 ntld8(const _Float16* p){ return __builtin_nontemporal_load((const f16x8*)p); }

// ---------- converts ----------
__global__ void k_cvt_x(const float4* __restrict__ x4, f16x4* __restrict__ xo, int n4){
  int i = blockIdx.x*blockDim.x + threadIdx.x;
  int stride = gridDim.x*blockDim.x;
  for (; i < n4; i += stride){
    float4 v = x4[i];
    f16x4 o = {(_Float16)v.x, (_Float16)v.y, (_Float16)v.z, (_Float16)v.w};
    xo[i] = o;
  }
}

// Wc[l][m][k] f16, m in gate-interleaved order: gate=m&3, hrow=m>>2;
// k<128 -> Whh[l][gate*128+hrow][k], k>=128 -> Wih[l][gate*128+hrow][k-128].
// biasp[l][hrow][gate] = bih+bhh (f32).
__global__ void k_cvt_w(const float* __restrict__ Wih, const float* __restrict__ Whh,
                        const float* __restrict__ bih, const float* __restrict__ bhh,
                        _Float16* __restrict__ Wc, float* __restrict__ biasp){
  int idx = blockIdx.x*blockDim.x + threadIdx.x;          // 3584*256 = 917504 exact
  int l    = idx >> 17;            // /(512*256)
  int rem  = idx & 131071;
  int m    = rem >> 8;
  int k    = rem & 255;
  int gate = m & 3, hrow = m >> 2;
  int srow = l*512 + gate*128 + hrow;
  float v = (k < 128) ? Whh[(size_t)srow*128 + k] : Wih[(size_t)srow*128 + (k-128)];
  Wc[idx] = (_Float16)v;
  if (idx < L_*512){
    int bl = idx >> 9, r = idx & 511;
    int bh = r >> 2, bg = r & 3;
    int s = bl*512 + bg*128 + bh;
    biasp[idx] = bih[s] + bhh[s];
  }
}

// ---------- fused wavefront recurrence ----------
// Grid = 56 WGs: wg = layer*8 + group; 512 thr, 16 batches per WG.
// z[512 x 16] = Wc(512x256) * [h;x](256x16) + bias via 32 MFMA/wave.
// Cross-layer dataflow is HAND-COHERENT: all inter-layer loads/stores are
// NON-TEMPORAL (no-allocate -> served by MALL, the XCD coherence point);
// flags are RELAXED agent-scope atomics (no buffer_wbl2 / buffer_inv cache
// ops, which an acquire/release pair would emit and which force every h
// write to HBM). Ordering: per-wave s_waitcnt vmcnt(0) + barrier BEFORE the
// flag bump guarantees nt data is in MALL when the flag becomes visible.
__global__ __launch_bounds__(512, 2) void k_recur(
    const _Float16* __restrict__ xcvt,
    _Float16* __restrict__ buf0, _Float16* __restrict__ buf1,
    const _Float16* __restrict__ Wc, const float4* __restrict__ biasp,
    int* __restrict__ flags){
  const int wg = blockIdx.x;
  const int layer = wg >> 3;
  const int g = wg & 7;
  const int tid = threadIdx.x;
  const int w = tid >> 6, l64 = tid & 63;
  const int q = l64 >> 4, i = l64 & 15;

  const _Float16* src = (layer == 0) ? xcvt : (((layer - 1) & 1) ? buf1 : buf0);
  _Float16* dst = (layer & 1) ? buf1 : buf0;

  __shared__ _Float16 hx[2][16][264];   // [h(128) | x(128) | pad]; 16B-aligned rows

  // A-frags: wf[mt][kt], row m = 16*(4w+mt)+i, k = 32kt+8q..+8
  f16x8 wf[4][8];
  {
    const _Float16* wbase = Wc + ((size_t)layer*512 + i)*256 + 8*q;
#pragma unroll
    for (int mt = 0; mt < 4; ++mt)
#pragma unroll
      for (int kt = 0; kt < 8; ++kt)
        wf[mt][kt] = *(const f16x8*)(wbase + (size_t)(16*(4*w+mt))*256 + 32*kt);
  }
  f32x4 bs[4];
#pragma unroll
  for (int mt = 0; mt < 4; ++mt){
    float4 bv = biasp[layer*128 + 4*(4*w+mt) + q];
    f32x4 t = {bv.x, bv.y, bv.z, bv.w};
    bs[mt] = t;
  }
  float cst[4] = {0.f, 0.f, 0.f, 0.f};

  // staging/flush roles
  const int bb = tid >> 5;          // batch 0..15
  const int cc = tid & 31;          // 4-elem chunk 0..31
  const size_t srow = ((size_t)(g*16 + bb))*T_*H_;
  const _Float16* xsrc = src + srow + cc*4;
  _Float16*       hdst = dst + srow + cc*4;
  int* fIn  = flags + ((layer - 1)*8 + g)*128;
  int* fOut = flags + (layer*8 + g)*128;

  auto poll = [&](int* p){
    if (tid == 0){
      while (__hip_atomic_load(p, __ATOMIC_RELAXED, __HIP_MEMORY_SCOPE_AGENT) == 0)
        __builtin_amdgcn_s_sleep(2);
    }
    __syncthreads();
  };

  // prologue: zero h-part, stage x row 0, prefetch row 1
  if (layer > 0) poll(fIn + 0);
  {
    f16x4 z4 = {(_Float16)0.f, (_Float16)0.f, (_Float16)0.f, (_Float16)0.f};
    *(f16x4*)&hx[0][bb][cc*4] = z4;                 // h part zero
    f16x4 x0 = ntld4(xsrc);                         // row 0
    *(f16x4*)&hx[0][bb][128 + cc*4] = x0;
  }
  f16x4 xn1 = ntld4(xsrc + (size_t)H_);             // row 1 (written at step 0)
  __syncthreads();

  for (int t = 0; t < T_; ++t){
    const int cur = t & 1, nxt = cur ^ 1;
    // poll for group of row t+2 BEFORE issuing its load
    if (layer > 0 && ((t + 2) & 7) == 0 && (t + 2) < T_) poll(fIn + ((t + 2) >> 3));
    int tp = (t + 2 < T_) ? t + 2 : T_ - 1;
    f16x4 xn2 = ntld4(xsrc + (size_t)tp*H_);        // 2-deep prefetch
    // flush row t-1 (h state entering this step) from hx[cur]
    f16x4 freg;
    if (t > 0) freg = *(const f16x4*)&hx[cur][bb][cc*4];
    // B-frags: 8 x ds_read_b128
    f16x8 bf[8];
#pragma unroll
    for (int kt = 0; kt < 8; ++kt)
      bf[kt] = *(const f16x8*)&hx[cur][i][32*kt + 8*q];
    // MFMA: 4 m-tiles x 8 k-tiles, C init = bias
    f32x4 acc[4];
#pragma unroll
    for (int mt = 0; mt < 4; ++mt){
      acc[mt] = bs[mt];
#pragma unroll
      for (int kt = 0; kt < 8; ++kt)
        acc[mt] = __builtin_amdgcn_mfma_f32_16x16x32_f16(wf[mt][kt], bf[kt], acc[mt], 0, 0, 0);
    }
    if (t > 0) ntst4(hdst + (size_t)(t - 1)*H_, freg);   // fire-and-forget to MALL
    // gates: 4 h-rows per lane (batch i, hrow 16w+4mt+q)
#pragma unroll
    for (int mt = 0; mt < 4; ++mt){
      f32x4 z = acc[mt];
      cst[mt] = fsig(z[1])*cst[mt] + fsig(z[0])*ftanh(z[2]);
      float h = fsig(z[3])*ftanh(cst[mt]);
      hx[nxt][i][4*(4*w + mt) + q] = (_Float16)h;
    }
    // x(t+1) into next buffer; rotate prefetch ring
    *(f16x4*)&hx[nxt][bb][128 + cc*4] = xn1;
    xn1 = xn2;
    asm volatile("s_waitcnt lgkmcnt(0)\n\ts_barrier" ::: "memory");
    // group boundary: rows <= t-1 in MALL after per-wave vmcnt(0) drain
    if (layer < 6 && t > 0 && (t & 7) == 0){
      asm volatile("s_waitcnt vmcnt(0)" ::: "memory");
      __syncthreads();
      if (tid == 0)
        (void)__hip_atomic_fetch_add(fOut + ((t >> 3) - 1), 1, __ATOMIC_RELAXED, __HIP_MEMORY_SCOPE_AGENT);
    }
  }
  // final flush: row 1023 lives in hx[0]
  {
    f16x4 freg = *(const f16x4*)&hx[0][bb][cc*4];
    ntst4(hdst + (size_t)(T_ - 1)*H_, freg);
  }
  if (layer < 6){
    asm volatile("s_waitcnt vmcnt(0)" ::: "memory");
    __syncthreads();
    if (tid == 0)
      (void)__hip_atomic_fetch_add(fOut + 127, 1, __ATOMIC_RELAXED, __HIP_MEMORY_SCOPE_AGENT);
  }
}

// ---------- attention (only head A-1 matters) + final linear + sigmoid ----------
__global__ __launch_bounds__(256) void k_attn(const _Float16* __restrict__ out,
                                              const float* __restrict__ Wa, const float* __restrict__ ba,
                                              const float* __restrict__ Wf, const float* __restrict__ bfv,
                                              float* __restrict__ y){
  int b = blockIdx.x, tid = threadIdx.x;
  __shared__ float was[H_];
  __shared__ float p[T_];
  __shared__ float red[64];
  __shared__ float app[256];
  if (tid < H_) was[tid] = Wa[127*H_ + tid];
  __syncthreads();
  float bav = ba[127];
  for (int t = tid; t < T_; t += 256){
    const _Float16* row = out + (size_t)(b*T_ + t)*H_;
    float acc = 0.f;
#pragma unroll
    for (int k = 0; k < H_; k += 8){
      f16x8 u = ntld8(row + k);
      acc += (float)u[0]*was[k+0] + (float)u[1]*was[k+1]
           + (float)u[2]*was[k+2] + (float)u[3]*was[k+3]
           + (float)u[4]*was[k+4] + (float)u[5]*was[k+5]
           + (float)u[6]*was[k+6] + (float)u[7]*was[k+7];
    }
    p[t] = ftanh(acc + bav);
  }
  __syncthreads();
  float m = -1e30f;
  for (int t = tid; t < T_; t += 256) m = fmaxf(m, p[t]);
  for (int off = 32; off; off >>= 1) m = fmaxf(m, __shfl_xor(m, off));
  if ((tid & 63) == 0) red[tid >> 6] = m;
  __syncthreads();
  if (tid == 0) red[8] = fmaxf(fmaxf(red[0], red[1]), fmaxf(red[2], red[3]));
  __syncthreads();
  float smax = red[8];
  float lsum = 0.f;
  for (int t = tid; t < T_; t += 256){
    float e = fexp2(1.44269504f*(p[t] - smax));
    p[t] = e; lsum += e;
  }
  for (int off = 32; off; off >>= 1) lsum += __shfl_xor(lsum, off);
  if ((tid & 63) == 0) red[16 + (tid >> 6)] = lsum;
  __syncthreads();
  float rden = frcp(red[16] + red[17] + red[18] + red[19]);
  int h = tid & (H_ - 1);
  int half = tid >> 7;
  float acc = 0.f;
  for (int t = half*512; t < half*512 + 512; ++t)
    acc += p[t] * (float)__builtin_nontemporal_load(out + (size_t)(b*T_ + t)*H_ + h);
  app[tid] = acc;
  __syncthreads();
  if (tid < H_){
    float applied = (app[tid] + app[tid + H_]) * rden;
    float v = applied * Wf[tid];
    for (int off = 32; off; off >>= 1) v += __shfl_xor(v, off);
    if (tid == 0)  red[32] = v;
    if (tid == 64) red[33] = v;
  }
  __syncthreads();
  if (tid == 0) y[b] = fsig(red[32] + red[33] + bfv[0]);
}

// ---------- launch ----------
extern "C" void kernel_launch(void* const* d_in, const int* in_sizes, int n_in,
                              void* d_out, int out_size, void* d_ws, size_t ws_size,
                              hipStream_t stream){
  const float* x   = (const float*)d_in[0];
  const float* Wih = (const float*)d_in[1];
  const float* Whh = (const float*)d_in[2];
  const float* bih = (const float*)d_in[3];
  const float* bhh = (const float*)d_in[4];
  const float* Wa  = (const float*)d_in[5];
  const float* ba  = (const float*)d_in[6];
  const float* Wf  = (const float*)d_in[7];
  const float* bfv = (const float*)d_in[8];
  float* y = (float*)d_out;

  char* ws = (char*)d_ws;
  size_t off = 0;
  auto alloc = [&](size_t bytes) -> void* {
    void* p = ws + off; off += (bytes + 255) & ~(size_t)255; return p;
  };
  _Float16* xcvt  = (_Float16*)alloc((size_t)M_*H_*2);       // 33.5 MB
  _Float16* buf0  = (_Float16*)alloc((size_t)M_*H_*2);       // 33.5 MB
  _Float16* buf1  = (_Float16*)alloc((size_t)M_*H_*2);       // 33.5 MB
  _Float16* Wc    = (_Float16*)alloc((size_t)L_*512*256*2);  // 1.8 MB
  float*    biasp = (float*)   alloc((size_t)L_*512*4);      // 14 KB
  int*      flags = (int*)     alloc((size_t)6*8*128*4);     // 24 KB

  hipMemsetAsync(flags, 0, (size_t)6*8*128*4, stream);
  k_cvt_x<<<2048, 256, 0, stream>>>((const float4*)x, (f16x4*)xcvt, M_*F_/4);
  k_cvt_w<<<3584, 256, 0, stream>>>(Wih, Whh, bih, bhh, Wc, biasp);
  k_recur<<<56, 512, 0, stream>>>(xcvt, buf0, buf1, Wc, (const float4*)biasp, flags);
  k_attn<<<128, 256, 0, stream>>>(buf0, Wa, ba, Wf, bfv, y);
}